// Round 2
// baseline (261.710 us; speedup 1.0000x reference)
//
#include <hip/hip_runtime.h>
#include <stdint.h>
#include <math.h>

// Problem geometry (fixed by reference):
//   logits [8,4096,1024] f32, primitives [1024,1024] f32
//   outputs: embeddings [8,4096,1024] f32 | indices [8,4096] (as f32) | counts [1024] (as f32)
#define NROWS   32768        // 8*4096
#define KDIM    1024
#define IDX_OFF 33554432     // 8*4096*1024
#define CNT_OFF 33587200     // IDX_OFF + 32768

__device__ __forceinline__ uint32_t rotl32(uint32_t x, int r) {
    return (x << r) | (x >> (32 - r));
}

// threefry2x32-20 with key (k0=0, k1=42), input words (x0=0, x1=ctr).
// Returns o0 ^ o1 — JAX partitionable 32-bit random_bits. (Validated round 1.)
__device__ __forceinline__ uint32_t threefry_bits(uint32_t ctr) {
    const uint32_t ks0 = 0u;
    const uint32_t ks1 = 42u;
    const uint32_t ks2 = 0x1BD11BDAu ^ 0u ^ 42u;   // 0x1BD11BF0

    uint32_t x0 = 0u + ks0;
    uint32_t x1 = ctr + ks1;

    x0 += x1; x1 = rotl32(x1, 13); x1 ^= x0;
    x0 += x1; x1 = rotl32(x1, 15); x1 ^= x0;
    x0 += x1; x1 = rotl32(x1, 26); x1 ^= x0;
    x0 += x1; x1 = rotl32(x1,  6); x1 ^= x0;
    x0 += ks1; x1 += ks2 + 1u;
    x0 += x1; x1 = rotl32(x1, 17); x1 ^= x0;
    x0 += x1; x1 = rotl32(x1, 29); x1 ^= x0;
    x0 += x1; x1 = rotl32(x1, 16); x1 ^= x0;
    x0 += x1; x1 = rotl32(x1, 24); x1 ^= x0;
    x0 += ks2; x1 += ks0 + 2u;
    x0 += x1; x1 = rotl32(x1, 13); x1 ^= x0;
    x0 += x1; x1 = rotl32(x1, 15); x1 ^= x0;
    x0 += x1; x1 = rotl32(x1, 26); x1 ^= x0;
    x0 += x1; x1 = rotl32(x1,  6); x1 ^= x0;
    x0 += ks0; x1 += ks1 + 3u;
    x0 += x1; x1 = rotl32(x1, 17); x1 ^= x0;
    x0 += x1; x1 = rotl32(x1, 29); x1 ^= x0;
    x0 += x1; x1 = rotl32(x1, 16); x1 ^= x0;
    x0 += x1; x1 = rotl32(x1, 24); x1 ^= x0;
    x0 += ks1; x1 += ks2 + 4u;
    x0 += x1; x1 = rotl32(x1, 13); x1 ^= x0;
    x0 += x1; x1 = rotl32(x1, 15); x1 ^= x0;
    x0 += x1; x1 = rotl32(x1, 26); x1 ^= x0;
    x0 += x1; x1 = rotl32(x1,  6); x1 ^= x0;
    x0 += ks2; x1 += ks0 + 5u;

    return x0 ^ x1;
}

// Fast gumbel: -log(-log(u)). Error bound ~1e-6 absolute for all candidates
// that can win the row argmax (see analysis: competitive u in [0.54,1), so the
// near-1 cancellation zone u>=0.875 goes through an exact-s polynomial; both
// hardware-log uses see inputs bounded away from 1).
__device__ __forceinline__ float fast_gumbel(uint32_t bits) {
    float f = __uint_as_float((bits >> 9) | 0x3f800000u) - 1.0f;  // [0,1)
    float u = fmaxf(f, 1.17549435e-38f);
    // inner: y = -ln(u)
    float s = 1.0f - u;                        // exact for u >= 0.5
    float p = fmaf(s, 0.14285714f, 0.16666667f);   // Taylor of (-ln(1-s)-s)/s^2
    p = fmaf(s, p, 0.2f);
    p = fmaf(s, p, 0.25f);
    p = fmaf(s, p, 0.33333333f);
    p = fmaf(s, p, 0.5f);
    float y_poly = fmaf(s * s, p, s);          // valid/accurate for s <= 0.125
    float y_hw   = -__logf(u);                 // v_log_f32 path, u < 0.875
    float y = (u >= 0.875f) ? y_poly : y_hw;
    // outer: competitive y in [6e-6, 0.61] — away from 1, hw log safe
    return -__logf(y);
}

// Round-1 precise chain (ROCm logf) — used only for flagged near-tie rows so
// that flagged decisions are bit-identical to the kernel that already passed.
__device__ float precise_z(const float* __restrict__ logits, uint32_t flat) {
    uint32_t bits = threefry_bits(flat);
    float f = __uint_as_float((bits >> 9) | 0x3f800000u) - 1.0f;
    float u = fmaxf(f, 1.17549435e-38f);
    float g = -logf(-logf(u));
    return logits[flat] + g;
}

// merge top-2 {v1,k1,v2,k2} <- with {w1,j1,w2,j2}; tie -> lower index
__device__ __forceinline__ void merge2(float& v1, int& k1, float& v2, int& k2,
                                       float w1, int j1, float w2, int j2) {
    bool bw = (w1 > v1) || (w1 == v1 && j1 < k1);
    float t1 = bw ? w1 : v1;  int tk1 = bw ? j1 : k1;
    float c  = bw ? v1 : w1;  int ck  = bw ? k1 : j1;   // loser of top comparison
    float d  = bw ? w2 : v2;  int dk  = bw ? j2 : k2;   // winner side's second
    bool cs = (c > d) || (c == d && ck < dk);
    v1 = t1; k1 = tk1;
    v2 = cs ? c : d;  k2 = cs ? ck : dk;
}

__global__ __launch_bounds__(256) void gumbel_argmax_gather(
    const float* __restrict__ logits,
    const float* __restrict__ prim,
    float* __restrict__ out,
    int* __restrict__ counts)
{
    const int row = blockIdx.x;          // 0..32767
    const int tid = threadIdx.x;         // 0..255
    const uint32_t base = (uint32_t)row * (uint32_t)KDIM;

    // --- per-thread top-2 over 4 contiguous columns (float4 load, ascending k)
    const float4 l4 = ((const float4*)(logits + base))[tid];
    float v1 = -INFINITY, v2 = -INFINITY;
    int   k1 = 0x7fffffff, k2 = 0x7fffffff;
    const float lv[4] = {l4.x, l4.y, l4.z, l4.w};
    #pragma unroll
    for (int j = 0; j < 4; ++j) {
        const int k = tid * 4 + j;
        const float g = fast_gumbel(threefry_bits(base + (uint32_t)k));
        const float z = lv[j] + g;       // argmax(z) == argmax(softmax(z/tau))
        if (z > v1)      { v2 = v1; k2 = k1; v1 = z; k1 = k; }
        else if (z > v2) { v2 = z;  k2 = k; }
    }

    // --- wave (64-lane) top-2 reduction
    #pragma unroll
    for (int off = 32; off > 0; off >>= 1) {
        const float w1 = __shfl_down(v1, off);
        const int   j1 = __shfl_down(k1, off);
        const float w2 = __shfl_down(v2, off);
        const int   j2 = __shfl_down(k2, off);
        merge2(v1, k1, v2, k2, w1, j1, w2, j2);
    }

    __shared__ float s_v1[4], s_v2[4];
    __shared__ int   s_k1[4], s_k2[4];
    __shared__ int   s_idx;
    const int wave = tid >> 6;
    if ((tid & 63) == 0) { s_v1[wave] = v1; s_k1[wave] = k1; s_v2[wave] = v2; s_k2[wave] = k2; }
    __syncthreads();

    if (tid == 0) {
        float a1 = s_v1[0], a2 = s_v2[0];
        int   b1 = s_k1[0], b2 = s_k2[0];
        #pragma unroll
        for (int w = 1; w < 4; ++w)
            merge2(a1, b1, a2, b2, s_v1[w], s_k1[w], s_v2[w], s_k2[w]);

        int kk = b1;
        // Near-tie safety net: fast-path |error| <= ~1e-6 << 1e-4 threshold.
        // Re-decide with the round-1 precise logf chain (expected ~3 rows total).
        if (a1 - a2 <= 1e-4f) {
            const float z1 = precise_z(logits, base + (uint32_t)b1);
            const float z2 = precise_z(logits, base + (uint32_t)b2);
            if (z2 > z1 || (z2 == z1 && b2 < b1)) kk = b2;
        }
        s_idx = kk;
        out[IDX_OFF + row] = (float)kk;          // indices stored as f32
        atomicAdd(&counts[kk], 1);
    }
    __syncthreads();

    // --- gather primitives[idx] row -> embeddings row (float4, coalesced)
    const int idx = s_idx;
    const float4* __restrict__ src = (const float4*)(prim + (size_t)idx * KDIM);
    float4* __restrict__ dst = (float4*)(out + (size_t)row * KDIM);
    dst[tid] = src[tid];
}

__global__ void counts_to_float(const int* __restrict__ counts, float* __restrict__ out) {
    const int t = blockIdx.x * blockDim.x + threadIdx.x;
    if (t < KDIM) out[t] = (float)counts[t];
}

extern "C" void kernel_launch(void* const* d_in, const int* in_sizes, int n_in,
                              void* d_out, int out_size, void* d_ws, size_t ws_size,
                              hipStream_t stream) {
    const float* logits = (const float*)d_in[0];   // [8,4096,1024] f32
    const float* prim   = (const float*)d_in[1];   // [1024,1024]   f32
    float* out = (float*)d_out;
    int*   cnt = (int*)d_ws;

    // d_ws is re-poisoned 0xAA before every launch — zero the histogram.
    hipMemsetAsync(d_ws, 0, KDIM * sizeof(int), stream);

    gumbel_argmax_gather<<<NROWS, 256, 0, stream>>>(logits, prim, out, cnt);
    counts_to_float<<<4, 256, 0, stream>>>(cnt, out + CNT_OFF);
}

// Round 3
// 252.819 us; speedup vs baseline: 1.0352x; 1.0352x over previous
//
#include <hip/hip_runtime.h>
#include <stdint.h>
#include <math.h>

// Problem geometry (fixed by reference):
//   logits [8,4096,1024] f32, primitives [1024,1024] f32
//   outputs: embeddings [8,4096,1024] f32 | indices [8,4096] (as f32) | counts [1024] (as f32)
#define NROWS   32768        // 8*4096
#define KDIM    1024
#define IDX_OFF 33554432     // 8*4096*1024
#define CNT_OFF 33587200     // IDX_OFF + 32768

// 1-instr rotate: v_alignbit_b32 (x:x) >> (32-r)
__device__ __forceinline__ uint32_t rotl32(uint32_t x, int r) {
    return __builtin_amdgcn_alignbit(x, x, (uint32_t)(32 - r));
}

// threefry2x32-20 with key (k0=0, k1=42), input (x0=0, x1=ctr), bits = o0^o1.
// JAX partitionable 32-bit random_bits — validated round 1.
__device__ __forceinline__ uint32_t threefry_bits(uint32_t ctr) {
    const uint32_t ks0 = 0u;
    const uint32_t ks1 = 42u;
    const uint32_t ks2 = 0x1BD11BDAu ^ 0u ^ 42u;   // 0x1BD11BF0

    uint32_t x0 = 0u + ks0;
    uint32_t x1 = ctr + ks1;

    x0 += x1; x1 = rotl32(x1, 13); x1 ^= x0;
    x0 += x1; x1 = rotl32(x1, 15); x1 ^= x0;
    x0 += x1; x1 = rotl32(x1, 26); x1 ^= x0;
    x0 += x1; x1 = rotl32(x1,  6); x1 ^= x0;
    x0 += ks1; x1 += ks2 + 1u;
    x0 += x1; x1 = rotl32(x1, 17); x1 ^= x0;
    x0 += x1; x1 = rotl32(x1, 29); x1 ^= x0;
    x0 += x1; x1 = rotl32(x1, 16); x1 ^= x0;
    x0 += x1; x1 = rotl32(x1, 24); x1 ^= x0;
    x0 += ks2; x1 += ks0 + 2u;
    x0 += x1; x1 = rotl32(x1, 13); x1 ^= x0;
    x0 += x1; x1 = rotl32(x1, 15); x1 ^= x0;
    x0 += x1; x1 = rotl32(x1, 26); x1 ^= x0;
    x0 += x1; x1 = rotl32(x1,  6); x1 ^= x0;
    x0 += ks0; x1 += ks1 + 3u;
    x0 += x1; x1 = rotl32(x1, 17); x1 ^= x0;
    x0 += x1; x1 = rotl32(x1, 29); x1 ^= x0;
    x0 += x1; x1 = rotl32(x1, 16); x1 ^= x0;
    x0 += x1; x1 = rotl32(x1, 24); x1 ^= x0;
    x0 += ks1; x1 += ks2 + 4u;
    x0 += x1; x1 = rotl32(x1, 13); x1 ^= x0;
    x0 += x1; x1 = rotl32(x1, 15); x1 ^= x0;
    x0 += x1; x1 = rotl32(x1, 26); x1 ^= x0;
    x0 += x1; x1 = rotl32(x1,  6); x1 ^= x0;
    x0 += ks2; x1 += ks0 + 5u;

    return x0 ^ x1;
}

// Fast monotone key: argmax_k(l_k + g_k) == argmax_k exp(l_k)/(-ln u_k).
// R > 0 always (normal-range float), so uint bits of R are order-isomorphic.
// Key = upper-22 bits of R | (k ^ 1023): v_max_u32 gives argmax with
// first-index tie-break at truncation granularity; near-ties are re-decided
// precisely (flag below).
__device__ __forceinline__ uint32_t fast_key(uint32_t bits, float l, int k) {
    float f = __uint_as_float((bits >> 9) | 0x3f800000u) - 1.0f;  // [0,1)
    float u = fmaxf(f, 1.17549435e-38f);
    // e = -ln(u): hw log is relative-accurate away from 1; near-1 use exact
    // s=1-u (Sterbenz) + series s(1+s(1/2+s(1/3+s/4))), rel err <= s^4/5 ~ 3e-6.
    float e_hw = -__logf(u);
    float s = 1.0f - u;
    float t = fmaf(s, 0.25f, 0.33333333f);
    t = fmaf(s, t, 0.5f);
    t = fmaf(s, t, 1.0f);
    float e = (u >= 0.9375f) ? (s * t) : e_hw;
    float R = __expf(l) * __builtin_amdgcn_rcpf(e);   // rel err ~1e-6 total
    return (__float_as_uint(R) & 0xFFFFFC00u) | (uint32_t)(k ^ 1023);
}

// Round-1 precise chain (libm logf) — ground truth for flagged near-tie rows;
// identical decisions to the kernel that already passed.
__device__ float precise_z(const float* __restrict__ logits, uint32_t flat) {
    uint32_t bits = threefry_bits(flat);
    float f = __uint_as_float((bits >> 9) | 0x3f800000u) - 1.0f;
    float u = fmaxf(f, 1.17549435e-38f);
    float g = -logf(-logf(u));
    return logits[flat] + g;
}

__global__ __launch_bounds__(256) void gumbel_argmax_gather(
    const float* __restrict__ logits,
    const float* __restrict__ prim,
    float* __restrict__ out,
    int* __restrict__ counts)
{
    const int row = blockIdx.x;          // 0..32767
    const int tid = threadIdx.x;         // 0..255
    const uint32_t base = (uint32_t)row * (uint32_t)KDIM;

    // --- per-thread top-2 packed keys over 4 contiguous columns
    const float4 l4 = ((const float4*)(logits + base))[tid];
    const float lv[4] = {l4.x, l4.y, l4.z, l4.w};
    uint32_t top1 = 0u, top2 = 0u;       // all real keys > 0
    #pragma unroll
    for (int j = 0; j < 4; ++j) {
        const int k = tid * 4 + j;
        const uint32_t key = fast_key(threefry_bits(base + (uint32_t)k), lv[j], k);
        const uint32_t mn = min(key, top1);
        top1 = max(key, top1);
        top2 = max(top2, mn);
    }

    // --- wave (64-lane) top-2 max reduction
    #pragma unroll
    for (int off = 32; off > 0; off >>= 1) {
        const uint32_t o1 = (uint32_t)__shfl_down((int)top1, off);
        const uint32_t o2 = (uint32_t)__shfl_down((int)top2, off);
        top2 = max(top2, max(o2, min(top1, o1)));
        top1 = max(top1, o1);
    }

    __shared__ uint32_t s_t1[4], s_t2[4];
    __shared__ int s_idx;
    __shared__ int s_flag;
    const int wave = tid >> 6;
    if ((tid & 63) == 0) { s_t1[wave] = top1; s_t2[wave] = top2; }
    __syncthreads();

    if (tid == 0) {
        uint32_t t1 = s_t1[0], t2 = s_t2[0];
        #pragma unroll
        for (int w = 1; w < 4; ++w) {
            const uint32_t o1 = s_t1[w], o2 = s_t2[w];
            t2 = max(t2, max(o2, min(t1, o1)));
            t1 = max(t1, o1);
        }
        // Flag if top-2 gap <= 7 units of 2^-13 relative: covers truncation
        // (1.2e-4) + fast-chain error (~2e-6) with 3x margin.
        const int flag = ((t1 >> 10) - (t2 >> 10)) <= 7u;
        s_flag = flag;
        if (!flag) s_idx = (int)((t1 & 1023u) ^ 1023u);
    }
    __syncthreads();

    // --- rare precise re-decision (block-uniform branch; ~16 rows / 32768)
    if (s_flag) {
        float bv = -INFINITY;
        int   bk = 0x7fffffff;
        #pragma unroll
        for (int j = 0; j < 4; ++j) {
            const int k = tid * 4 + j;
            const float z = precise_z(logits, base + (uint32_t)k);
            if (z > bv) { bv = z; bk = k; }   // ascending k: first-index ties
        }
        #pragma unroll
        for (int off = 32; off > 0; off >>= 1) {
            const float ov = __shfl_down(bv, off);
            const int   ok = __shfl_down(bk, off);
            if (ov > bv || (ov == bv && ok < bk)) { bv = ov; bk = ok; }
        }
        __shared__ float s_v[4];
        __shared__ int   s_k[4];
        if ((tid & 63) == 0) { s_v[wave] = bv; s_k[wave] = bk; }
        __syncthreads();
        if (tid == 0) {
            float v = s_v[0]; int kk = s_k[0];
            #pragma unroll
            for (int w = 1; w < 4; ++w)
                if (s_v[w] > v || (s_v[w] == v && s_k[w] < kk)) { v = s_v[w]; kk = s_k[w]; }
            s_idx = kk;
        }
        __syncthreads();
    }

    const int idx = s_idx;
    if (tid == 0) {
        out[IDX_OFF + row] = (float)idx;         // indices stored as f32
        atomicAdd(&counts[idx], 1);
    }

    // --- gather primitives[idx] row -> embeddings row (float4, coalesced)
    const float4* __restrict__ src = (const float4*)(prim + (size_t)idx * KDIM);
    float4* __restrict__ dst = (float4*)(out + (size_t)row * KDIM);
    dst[tid] = src[tid];
}

__global__ void counts_to_float(const int* __restrict__ counts, float* __restrict__ out) {
    const int t = blockIdx.x * blockDim.x + threadIdx.x;
    if (t < KDIM) out[t] = (float)counts[t];
}

extern "C" void kernel_launch(void* const* d_in, const int* in_sizes, int n_in,
                              void* d_out, int out_size, void* d_ws, size_t ws_size,
                              hipStream_t stream) {
    const float* logits = (const float*)d_in[0];   // [8,4096,1024] f32
    const float* prim   = (const float*)d_in[1];   // [1024,1024]   f32
    float* out = (float*)d_out;
    int*   cnt = (int*)d_ws;

    // d_ws is re-poisoned 0xAA before every launch — zero the histogram.
    hipMemsetAsync(d_ws, 0, KDIM * sizeof(int), stream);

    gumbel_argmax_gather<<<NROWS, 256, 0, stream>>>(logits, prim, out, cnt);
    counts_to_float<<<4, 256, 0, stream>>>(cnt, out + CNT_OFF);
}